// Round 10
// baseline (109.606 us; speedup 1.0000x reference)
//
#include <hip/hip_runtime.h>

#define BS 16
#define SEQL 2048
#define NH 16
#define PD 64
#define ND 16
#define LB 64
#define NC 32          // SEQL / LB
#define NHP (NH * PD)  // 1024
#define NHN (NH * ND)  // 256
#define PH 32          // p-columns per block (half)

typedef __attribute__((ext_vector_type(8))) short bf16x8;
typedef __attribute__((ext_vector_type(4))) float f32x4;

static __device__ __forceinline__ unsigned short f2bf(float x) {
  unsigned int u = __float_as_uint(x);
  return (unsigned short)((u + 0x7FFFu + ((u >> 16) & 1u)) >> 16);  // RNE
}
static __device__ __forceinline__ unsigned int pk2(float a, float b) {
  return (unsigned int)f2bf(a) | ((unsigned int)f2bf(b) << 16);
}

// LDS-only barrier (drains lgkmcnt, NOT vmcnt): global prefetch loads stay in
// flight across it. All cross-wave data flows through LDS.
static __device__ __forceinline__ void barrier_lds() {
  __builtin_amdgcn_sched_barrier(0);
  asm volatile("s_waitcnt lgkmcnt(0)" ::: "memory");
  __builtin_amdgcn_s_barrier();
  __builtin_amdgcn_sched_barrier(0);
}

// k-slot permutation pi: slot m=8g+u holds l = 4g+u (u<4) or 16+4g+(u-4)
// (u>=4) within each 32-l pair; makes the mtile MFMA output order directly
// usable as an A-fragment (M never touches LDS). X^T and (dec*B)^T staged
// with the SAME permutation (MFMA invariant to consistent k-permute).
static __device__ __forceinline__ int invperm(int l) {
  const int jp = l >> 5, v = l & 31;
  return jp * 32 + (v < 16 ? (((v >> 2) << 3) | (v & 3))
                           : ((((v - 16) >> 2) << 3) | 4 | ((v - 16) & 3)));
}

// Grid 512 = 256 (b,h) x 2 p-halves; 256 threads = 4 waves. TWO independent
// blocks per CU: one block's barrier/HBM stalls hide under the other's issue
// stream. Each block: 32 sequential chunks, ONE lgkm-barrier per chunk,
// double-buffered staging, M in registers, ST[32p][16n] ping-pong in LDS.
__global__ __launch_bounds__(256, 2) void ssd_fused(
    const float* __restrict__ Xg, const float* __restrict__ Ag,
    const float* __restrict__ Bg, const float* __restrict__ Cg,
    float* __restrict__ Yg) {
  const int bh = blockIdx.x & 255;
  const int phalf = blockIdx.x >> 8;   // siblings 256 apart -> same XCD residue
  const int h = bh & (NH - 1);
  const int b = bh >> 4;
  const int pc0 = h * PD + phalf * PH;
  const int t = threadIdx.x;
  const int w = t >> 6;    // wave 0..3
  const int lane = t & 63;
  const int g = lane >> 4;
  const int cc = lane & 15;

  __shared__ __align__(16) unsigned short sXt[2][PH][64];       // X^T permuted
  __shared__ __align__(16) unsigned short sB[2][LB][ND + 8];
  __shared__ __align__(16) unsigned short sC[2][LB][ND + 8];    // C' = e_l*C
  __shared__ __align__(16) unsigned short sBdT[2][ND][LB + 8];  // (dec*B)^T perm
  __shared__ __align__(16) float sSTf[2][PH][ND + 4];           // ST fp32 ping-pong
  __shared__ __align__(16) unsigned short sSTb[2][PH][ND + 8];  // ST bf16 mirror
  __shared__ float sER[NC][LB];   // exp(+acs)
  __shared__ float sRR[NC][LB];   // exp(-acs)
  __shared__ float sEtot[NC];

  // ---- prologue: decay tables for ALL chunks (wave w -> chunks 8w..8w+7) ----
  {
    float av[8];
#pragma unroll
    for (int k = 0; k < 8; ++k)
      av[k] = Ag[((size_t)(b * SEQL + (w * 8 + k) * LB + lane)) * NH + h];
#pragma unroll
    for (int k = 0; k < 8; ++k) {
      const int c = w * 8 + k;
      float v = av[k];
#pragma unroll
      for (int d = 1; d < 64; d <<= 1) {
        float o = __shfl_up(v, d, 64);
        if (lane >= d) v += o;
      }
      const float e = expf(v);
      sER[c][lane] = e;
      sRR[c][lane] = expf(-v);
      if (lane == 63) sEtot[c] = e;
    }
  }
  for (int i = t; i < PH * (ND + 4); i += 256) ((float*)sSTf[0])[i] = 0.f;
  for (int i = t; i < PH * (ND + 8); i += 256) ((unsigned short*)sSTb[0])[i] = 0;
  __syncthreads();  // tables + ST init visible before any STAGE reads them

  // thread maps
  const int xl0 = (t >> 3) * 2, xp0 = (t & 7) * 4;   // X: 2 l x 4 local-p
  const int bl = t >> 2, bn0 = (t & 3) * 4;          // B/C: 1 row x 4 n
  const int btn = t >> 4, btl = (t & 15) * 4;        // BdT: 1 n x 4 l
  const int mX = invperm(xl0);
  int mb[4];
#pragma unroll
  for (int j = 0; j < 4; ++j) mb[j] = invperm(btl + j);

  float4 px0, px1, pb4, pc4;
  float pt0, pt1, pt2, pt3;

#define PREF(ci) do { \
    const size_t s0_ = (size_t)(b * SEQL + (ci) * LB); \
    px0 = *(const float4*)&Xg[(s0_ + xl0) * NHP + pc0 + xp0]; \
    px1 = *(const float4*)&Xg[(s0_ + xl0 + 1) * NHP + pc0 + xp0]; \
    pb4 = *(const float4*)&Bg[(s0_ + bl) * NHN + h * ND + bn0]; \
    pc4 = *(const float4*)&Cg[(s0_ + bl) * NHN + h * ND + bn0]; \
    pt0 = Bg[(s0_ + btl) * NHN + h * ND + btn]; \
    pt1 = Bg[(s0_ + btl + 1) * NHN + h * ND + btn]; \
    pt2 = Bg[(s0_ + btl + 2) * NHN + h * ND + btn]; \
    pt3 = Bg[(s0_ + btl + 3) * NHN + h * ND + btn]; \
  } while (0)

#define STAGE(bufi, ci) do { \
    _Pragma("unroll") \
    for (int j_ = 0; j_ < 4; ++j_) { \
      const int p_ = xp0 + j_; \
      const int mm_ = ((((mX >> 3) ^ ((p_ >> 3) & 7)) << 3) | (mX & 7)); \
      *(unsigned int*)&sXt[bufi][p_][mm_] = pk2((&px0.x)[j_], (&px1.x)[j_]); \
    } \
    { const float el_ = sER[ci][bl]; \
      uint2 ub_, uc_; \
      ub_.x = pk2(pb4.x, pb4.y); ub_.y = pk2(pb4.z, pb4.w); \
      uc_.x = pk2(el_ * pc4.x, el_ * pc4.y); \
      uc_.y = pk2(el_ * pc4.z, el_ * pc4.w); \
      *(uint2*)&sB[bufi][bl][bn0] = ub_; \
      *(uint2*)&sC[bufi][bl][bn0] = uc_; } \
    { const float et_ = sEtot[ci]; \
      sBdT[bufi][btn][mb[0]] = f2bf(et_ * sRR[ci][btl] * pt0); \
      sBdT[bufi][btn][mb[1]] = f2bf(et_ * sRR[ci][btl + 1] * pt1); \
      sBdT[bufi][btn][mb[2]] = f2bf(et_ * sRR[ci][btl + 2] * pt2); \
      sBdT[bufi][btn][mb[3]] = f2bf(et_ * sRR[ci][btl + 3] * pt3); } \
  } while (0)

  const bf16x8 zf8 = {0, 0, 0, 0, 0, 0, 0, 0};
  auto xfrag = [&](int buf, int p_, int kb) -> bf16x8 {
    return *(const bf16x8*)&sXt[buf][p_][(kb ^ ((p_ >> 3) & 7)) << 3];
  };

  PREF(0);
  STAGE(0, 0);
  PREF(1);
  barrier_lds();  // stage(0) visible

  const int l = w * 16 + cc;  // wave w owns l-block w

  for (int c = 0; c < NC; ++c) {
    const int db = c & 1, nb = db ^ 1;

    // ---- M-frags in registers for l-block w ----
    bf16x8 cf = zf8;
    if (g < 2) cf = *(const bf16x8*)&sC[db][l][g * 8];
    auto mtile = [&](int sb, bool mask) -> uint2 {
      bf16x8 bfr = zf8;
      if (g < 2) bfr = *(const bf16x8*)&sB[db][sb * 16 + cc][g * 8];
      f32x4 z4 = {0.f, 0.f, 0.f, 0.f};
      f32x4 d = __builtin_amdgcn_mfma_f32_16x16x32_bf16(bfr, cf, z4, 0, 0, 0);
      // lane holds D'[s = sb*16+4g+r][l]
      float m[4];
#pragma unroll
      for (int r = 0; r < 4; ++r) {
        m[r] = d[r] * sRR[c][sb * 16 + 4 * g + r];
        if (mask && (4 * g + r) > cc) m[r] = 0.f;
      }
      return make_uint2(pk2(m[0], m[1]), pk2(m[2], m[3]));
    };
    union { bf16x8 v; unsigned int u[4]; } mf0, mf1;
    mf0.u[0] = mf0.u[1] = mf0.u[2] = mf0.u[3] = 0u;
    mf1.u[0] = mf1.u[1] = mf1.u[2] = mf1.u[3] = 0u;
    if (w == 0) {
      const uint2 t0 = mtile(0, true);
      mf0.u[0] = t0.x; mf0.u[1] = t0.y;
    } else if (w == 1) {
      const uint2 t0 = mtile(0, false), t1 = mtile(1, true);
      mf0.u[0] = t0.x; mf0.u[1] = t0.y; mf0.u[2] = t1.x; mf0.u[3] = t1.y;
    } else if (w == 2) {
      const uint2 t0 = mtile(0, false), t1 = mtile(1, false), t2 = mtile(2, true);
      mf0.u[0] = t0.x; mf0.u[1] = t0.y; mf0.u[2] = t1.x; mf0.u[3] = t1.y;
      mf1.u[0] = t2.x; mf1.u[1] = t2.y;
    } else {
      const uint2 t0 = mtile(0, false), t1 = mtile(1, false);
      const uint2 t2 = mtile(2, false), t3 = mtile(3, true);
      mf0.u[0] = t0.x; mf0.u[1] = t0.y; mf0.u[2] = t1.x; mf0.u[3] = t1.y;
      mf1.u[0] = t2.x; mf1.u[1] = t2.y; mf1.u[2] = t3.x; mf1.u[3] = t3.y;
    }

    // ---- Y tiles: 2 local p-blocks ----
#pragma unroll
    for (int pbi = 0; pbi < 2; ++pbi) {
      const int p = pbi * 16 + cc;
      bf16x8 stf = zf8;
      if (g < 2) stf = *(const bf16x8*)&sSTb[db][p][g * 8];
      f32x4 acc = {0.f, 0.f, 0.f, 0.f};
      acc = __builtin_amdgcn_mfma_f32_16x16x32_bf16(cf, stf, acc, 0, 0, 0);
      acc = __builtin_amdgcn_mfma_f32_16x16x32_bf16(mf0.v, xfrag(db, p, g), acc, 0, 0, 0);
      if (w >= 2)
        acc = __builtin_amdgcn_mfma_f32_16x16x32_bf16(mf1.v, xfrag(db, p, 4 + g), acc, 0, 0, 0);
      const size_t yb =
          ((size_t)(b * SEQL + c * LB + w * 16 + 4 * g)) * NHP + pc0 + p;
#pragma unroll
      for (int r = 0; r < 4; ++r) Yg[yb + (size_t)r * NHP] = acc[r];
    }

    // ---- S/ST update on light waves (0,1): one p-block each ----
    if (w < 2) {
      const int pS = w * 16 + cc;
      bf16x8 ad0 = *(const bf16x8*)&sBdT[db][cc][g * 8];
      bf16x8 ad1 = *(const bf16x8*)&sBdT[db][cc][32 + g * 8];
      f32x4 s4 = {0.f, 0.f, 0.f, 0.f};
      s4 = __builtin_amdgcn_mfma_f32_16x16x32_bf16(ad0, xfrag(db, pS, g), s4, 0, 0, 0);
      s4 = __builtin_amdgcn_mfma_f32_16x16x32_bf16(ad1, xfrag(db, pS, 4 + g), s4, 0, 0, 0);
      const float etot = sEtot[c];
      // lane holds S[n = 4g+r][pS]
      float4 old = *(const float4*)&sSTf[db][pS][4 * g];
      float4 nw;
      nw.x = old.x * etot + s4[0];
      nw.y = old.y * etot + s4[1];
      nw.z = old.z * etot + s4[2];
      nw.w = old.w * etot + s4[3];
      *(float4*)&sSTf[nb][pS][4 * g] = nw;
      uint2 ub;
      ub.x = pk2(nw.x, nw.y);
      ub.y = pk2(nw.z, nw.w);
      *(uint2*)&sSTb[nb][pS][4 * g] = ub;
    }

    // ---- stage chunk c+1 into buf nb (overlaps compute above) ----
    if (c + 1 < NC) {
      STAGE(nb, c + 1);
      if (c + 2 < NC) PREF(c + 2);
    }
    barrier_lds();  // staged data + ST[nb] visible
  }
#undef PREF
#undef STAGE
}

extern "C" void kernel_launch(void* const* d_in, const int* in_sizes, int n_in,
                              void* d_out, int out_size, void* d_ws, size_t ws_size,
                              hipStream_t stream) {
  (void)in_sizes; (void)n_in; (void)out_size; (void)d_ws; (void)ws_size;
  const float* X = (const float*)d_in[0];
  const float* A = (const float*)d_in[1];
  const float* B = (const float*)d_in[2];
  const float* C = (const float*)d_in[3];
  float* Y = (float*)d_out;
  ssd_fused<<<2 * BS * NH, 256, 0, stream>>>(X, A, B, C, Y);
}

// Round 11
// 105.323 us; speedup vs baseline: 1.0407x; 1.0407x over previous
//
#include <hip/hip_runtime.h>

#define BS 16
#define SEQL 2048
#define NH 16
#define PD 64
#define ND 16
#define LB 64
#define NC 32          // SEQL / LB
#define NHP (NH * PD)  // 1024
#define NHN (NH * ND)  // 256

typedef __attribute__((ext_vector_type(8))) short bf16x8;
typedef __attribute__((ext_vector_type(4))) float f32x4;

static __device__ __forceinline__ unsigned short f2bf(float x) {
  unsigned int u = __float_as_uint(x);
  return (unsigned short)((u + 0x7FFFu + ((u >> 16) & 1u)) >> 16);  // RNE
}
static __device__ __forceinline__ unsigned int pk2(float a, float b) {
  return (unsigned int)f2bf(a) | ((unsigned int)f2bf(b) << 16);
}

// LDS-only barrier (drains lgkmcnt, NOT vmcnt): global prefetch loads stay in
// flight across it.
static __device__ __forceinline__ void barrier_lds() {
  __builtin_amdgcn_sched_barrier(0);
  asm volatile("s_waitcnt lgkmcnt(0)" ::: "memory");
  __builtin_amdgcn_s_barrier();
  __builtin_amdgcn_sched_barrier(0);
}

// k-slot permutation pi (see R8/R9): makes mtile MFMA output directly usable
// as an A-fragment; X^T and (dec*B)^T staged with the same permutation.
static __device__ __forceinline__ int invperm(int l) {
  const int jp = l >> 5, v = l & 31;
  return jp * 32 + (v < 16 ? (((v >> 2) << 3) | (v & 3))
                           : ((((v - 16) >> 2) << 3) | 4 | ((v - 16) & 3)));
}

// One block per (b,h), 8 waves. ST is WAVE-PRIVATE: each wave redundantly
// computes S for its own 2 p-blocks (fp32 masters in registers; bf16 B-frag
// re-layout via a wave-private LDS patch, same-wave write->read, no barrier).
// The only cross-wave dependency left is staging rotation -> 2 chunks per
// barrier window (16 windows, 4 staging slots).
__global__ __launch_bounds__(512) void ssd_fused(
    const float* __restrict__ Xg, const float* __restrict__ Ag,
    const float* __restrict__ Bg, const float* __restrict__ Cg,
    float* __restrict__ Yg) {
  const int h = blockIdx.x & (NH - 1);
  const int b = blockIdx.x >> 4;
  const int t = threadIdx.x;
  const int w = t >> 6;
  const int lane = t & 63;
  const int g = lane >> 4;
  const int cc = lane & 15;

  __shared__ __align__(16) unsigned short sXt[4][PD][64];      // X^T perm+swz
  __shared__ __align__(16) unsigned short sB[4][LB][ND + 8];
  __shared__ __align__(16) unsigned short sC[4][LB][ND + 8];   // C' = e_l*C
  __shared__ __align__(16) unsigned short sBdT[4][ND][LB + 8]; // (dec*B)^T perm
  __shared__ __align__(16) unsigned short sSTp[8][2][16][24];  // wave-private ST
  __shared__ float sER[NC][LB];
  __shared__ float sRR[NC][LB];
  __shared__ float sEtot[NC];

  // ---- prologue: decay tables for ALL chunks ----
  {
    float av[4];
#pragma unroll
    for (int k = 0; k < 4; ++k)
      av[k] = Ag[((size_t)(b * SEQL + (w + 8 * k) * LB + lane)) * NH + h];
#pragma unroll
    for (int k = 0; k < 4; ++k) {
      const int c = w + 8 * k;
      float v = av[k];
#pragma unroll
      for (int d = 1; d < 64; d <<= 1) {
        float o = __shfl_up(v, d, 64);
        if (lane >= d) v += o;
      }
      const float e = expf(v);
      sER[c][lane] = e;
      sRR[c][lane] = expf(-v);
      if (lane == 63) sEtot[c] = e;
    }
  }
  for (int i = t; i < 8 * 2 * 16 * 24; i += 512) ((unsigned short*)sSTp)[i] = 0;

  // thread maps (staging)
  const int xl0 = (t >> 4) * 2, xp0 = (t & 15) * 4;  // X: 2 l x 4 p
  const int bl = t >> 3, bn0 = (t & 7) * 2;          // B/C: 1 row x 2 n
  const int n_bt = t >> 5, l_bt = (t & 31) * 2;      // BdT: 1 n x 2 l
  const int mX = invperm(xl0);
  const int mB = invperm(l_bt);   // l_bt even; invperm(l+1)=invperm(l)+? not in
  const int mB1 = invperm(l_bt + 1);                 // general -> compute both

  float4 px0A, px1A, px0B, px1B;
  float2 pb2A, pc2A, pb2B, pc2B;
  float pbAA, pbBA, pbAB, pbBB;

#define PREFA(ci) do { \
    const size_t s0_ = (size_t)(b * SEQL + (ci) * LB); \
    px0A = *(const float4*)&Xg[(s0_ + xl0) * NHP + h * PD + xp0]; \
    px1A = *(const float4*)&Xg[(s0_ + xl0 + 1) * NHP + h * PD + xp0]; \
    pb2A = *(const float2*)&Bg[(s0_ + bl) * NHN + h * ND + bn0]; \
    pc2A = *(const float2*)&Cg[(s0_ + bl) * NHN + h * ND + bn0]; \
    pbAA = Bg[(s0_ + l_bt) * NHN + h * ND + n_bt]; \
    pbBA = Bg[(s0_ + l_bt + 1) * NHN + h * ND + n_bt]; \
  } while (0)
#define PREFB(ci) do { \
    const size_t s0_ = (size_t)(b * SEQL + (ci) * LB); \
    px0B = *(const float4*)&Xg[(s0_ + xl0) * NHP + h * PD + xp0]; \
    px1B = *(const float4*)&Xg[(s0_ + xl0 + 1) * NHP + h * PD + xp0]; \
    pb2B = *(const float2*)&Bg[(s0_ + bl) * NHN + h * ND + bn0]; \
    pc2B = *(const float2*)&Cg[(s0_ + bl) * NHN + h * ND + bn0]; \
    pbAB = Bg[(s0_ + l_bt) * NHN + h * ND + n_bt]; \
    pbBB = Bg[(s0_ + l_bt + 1) * NHN + h * ND + n_bt]; \
  } while (0)

#define STAGE(px0_, px1_, pb2_, pc2_, pbA_, pbB_, slot, ci) do { \
    _Pragma("unroll") \
    for (int j_ = 0; j_ < 4; ++j_) { \
      const int p_ = xp0 + j_; \
      const int mm_ = ((((mX >> 3) ^ ((p_ >> 3) & 7)) << 3) | (mX & 7)); \
      *(unsigned int*)&sXt[slot][p_][mm_] = pk2((&px0_.x)[j_], (&px1_.x)[j_]); \
    } \
    { const float el_ = sER[ci][bl]; \
      *(unsigned int*)&sB[slot][bl][bn0] = pk2(pb2_.x, pb2_.y); \
      *(unsigned int*)&sC[slot][bl][bn0] = pk2(el_ * pc2_.x, el_ * pc2_.y); } \
    { const float et_ = sEtot[ci]; \
      sBdT[slot][n_bt][mB]  = f2bf(et_ * sRR[ci][l_bt] * pbA_); \
      sBdT[slot][n_bt][mB1] = f2bf(et_ * sRR[ci][l_bt + 1] * pbB_); } \
  } while (0)

  const bf16x8 zf8 = {0, 0, 0, 0, 0, 0, 0, 0};
  auto xfrag = [&](int slot, int p_, int kb) -> bf16x8 {
    return *(const bf16x8*)&sXt[slot][p_][(kb ^ ((p_ >> 3) & 7)) << 3];
  };

  const int lb = w & 3;         // l-block (waves w and w+4 duplicate M)
  const int pb0 = (w >> 2) * 2; // this wave's two p-blocks
  const int l = lb * 16 + cc;
  float stm[2][4];              // fp32 ST masters: [pbi][r] = ST[n=4g+r][p]
#pragma unroll
  for (int i = 0; i < 2; ++i)
#pragma unroll
    for (int r = 0; r < 4; ++r) stm[i][r] = 0.f;

  __syncthreads();  // tables + patch zero visible

  PREFA(0);
  PREFB(1);
  STAGE(px0A, px1A, pb2A, pc2A, pbAA, pbBA, 0, 0);
  STAGE(px0B, px1B, pb2B, pc2B, pbAB, pbBB, 1, 1);
  PREFA(2);
  PREFB(3);
  barrier_lds();

  auto compute_chunk = [&](int slot, int c) {
    bf16x8 cf = zf8;
    if (g < 2) cf = *(const bf16x8*)&sC[slot][l][g * 8];
    auto mtile = [&](int sb, bool mask) -> uint2 {
      bf16x8 bfr = zf8;
      if (g < 2) bfr = *(const bf16x8*)&sB[slot][sb * 16 + cc][g * 8];
      f32x4 z4 = {0.f, 0.f, 0.f, 0.f};
      f32x4 d = __builtin_amdgcn_mfma_f32_16x16x32_bf16(bfr, cf, z4, 0, 0, 0);
      float m[4];
#pragma unroll
      for (int r = 0; r < 4; ++r) {
        m[r] = d[r] * sRR[c][sb * 16 + 4 * g + r];
        if (mask && (4 * g + r) > cc) m[r] = 0.f;
      }
      return make_uint2(pk2(m[0], m[1]), pk2(m[2], m[3]));
    };
    union { bf16x8 v; unsigned int u[4]; } mf0, mf1;
    mf0.u[0] = mf0.u[1] = mf0.u[2] = mf0.u[3] = 0u;
    mf1.u[0] = mf1.u[1] = mf1.u[2] = mf1.u[3] = 0u;
    if (lb == 0) {
      const uint2 t0 = mtile(0, true);
      mf0.u[0] = t0.x; mf0.u[1] = t0.y;
    } else if (lb == 1) {
      const uint2 t0 = mtile(0, false), t1 = mtile(1, true);
      mf0.u[0] = t0.x; mf0.u[1] = t0.y; mf0.u[2] = t1.x; mf0.u[3] = t1.y;
    } else if (lb == 2) {
      const uint2 t0 = mtile(0, false), t1 = mtile(1, false), t2 = mtile(2, true);
      mf0.u[0] = t0.x; mf0.u[1] = t0.y; mf0.u[2] = t1.x; mf0.u[3] = t1.y;
      mf1.u[0] = t2.x; mf1.u[1] = t2.y;
    } else {
      const uint2 t0 = mtile(0, false), t1 = mtile(1, false);
      const uint2 t2 = mtile(2, false), t3 = mtile(3, true);
      mf0.u[0] = t0.x; mf0.u[1] = t0.y; mf0.u[2] = t1.x; mf0.u[3] = t1.y;
      mf1.u[0] = t2.x; mf1.u[1] = t2.y; mf1.u[2] = t3.x; mf1.u[3] = t3.y;
    }
    // S A-frags (shared across this wave's p-blocks)
    bf16x8 ad0 = *(const bf16x8*)&sBdT[slot][cc][g * 8];
    bf16x8 ad1 = *(const bf16x8*)&sBdT[slot][cc][32 + g * 8];
    const float etot = sEtot[c];
#pragma unroll
    for (int pbi = 0; pbi < 2; ++pbi) {
      const int p = (pb0 + pbi) * 16 + cc;
      // Y = C'@ST^T + M@X   (ST entering chunk c, from private patch)
      bf16x8 stf = zf8;
      if (g < 2) stf = *(const bf16x8*)&sSTp[w][pbi][cc][g * 8];
      f32x4 acc = {0.f, 0.f, 0.f, 0.f};
      acc = __builtin_amdgcn_mfma_f32_16x16x32_bf16(cf, stf, acc, 0, 0, 0);
      acc = __builtin_amdgcn_mfma_f32_16x16x32_bf16(mf0.v, xfrag(slot, p, g), acc, 0, 0, 0);
      if (lb >= 2)
        acc = __builtin_amdgcn_mfma_f32_16x16x32_bf16(mf1.v, xfrag(slot, p, 4 + g), acc, 0, 0, 0);
      const size_t yb =
          ((size_t)(b * SEQL + c * LB + lb * 16 + 4 * g)) * NHP + h * PD + p;
#pragma unroll
      for (int r = 0; r < 4; ++r) Yg[yb + (size_t)r * NHP] = acc[r];
      // S (redundant per wave) + private ST update, lane holds S[n=4g+r][p]
      f32x4 s4 = {0.f, 0.f, 0.f, 0.f};
      s4 = __builtin_amdgcn_mfma_f32_16x16x32_bf16(ad0, xfrag(slot, p, g), s4, 0, 0, 0);
      s4 = __builtin_amdgcn_mfma_f32_16x16x32_bf16(ad1, xfrag(slot, p, 4 + g), s4, 0, 0, 0);
#pragma unroll
      for (int r = 0; r < 4; ++r) stm[pbi][r] = stm[pbi][r] * etot + s4[r];
      uint2 ub;
      ub.x = pk2(stm[pbi][0], stm[pbi][1]);
      ub.y = pk2(stm[pbi][2], stm[pbi][3]);
      *(uint2*)&sSTp[w][pbi][cc][4 * g] = ub;   // same-wave read next chunk
    }
  };

  for (int k = 0; k < 16; ++k) {
    const int sA = (k & 1) * 2, sB_ = sA + 1;
    compute_chunk(sA, 2 * k);
    compute_chunk(sB_, 2 * k + 1);
    if (k < 15) {
      const int dA = (~k & 1) * 2, dB = dA + 1;
      STAGE(px0A, px1A, pb2A, pc2A, pbAA, pbBA, dA, 2 * k + 2);
      STAGE(px0B, px1B, pb2B, pc2B, pbAB, pbBB, dB, 2 * k + 3);
      if (k < 14) {
        PREFA(2 * k + 4);
        PREFB(2 * k + 5);
      }
    }
    barrier_lds();
  }
#undef PREFA
#undef PREFB
#undef STAGE
}

extern "C" void kernel_launch(void* const* d_in, const int* in_sizes, int n_in,
                              void* d_out, int out_size, void* d_ws, size_t ws_size,
                              hipStream_t stream) {
  (void)in_sizes; (void)n_in; (void)out_size; (void)d_ws; (void)ws_size;
  const float* X = (const float*)d_in[0];
  const float* A = (const float*)d_in[1];
  const float* B = (const float*)d_in[2];
  const float* C = (const float*)d_in[3];
  float* Y = (float*)d_out;
  ssd_fused<<<BS * NH, 512, 0, stream>>>(X, A, B, C, Y);
}

// Round 14
// 84.904 us; speedup vs baseline: 1.2909x; 1.2405x over previous
//
#include <hip/hip_runtime.h>

#define BS 16
#define SEQL 2048
#define NH 16
#define PD 64
#define ND 16
#define LB 64
#define NC 32          // SEQL / LB
#define NHP (NH * PD)  // 1024
#define NHN (NH * ND)  // 256

typedef __attribute__((ext_vector_type(8))) short bf16x8;
typedef __attribute__((ext_vector_type(4))) float f32x4;

static __device__ __forceinline__ unsigned short f2bf(float x) {
  unsigned int u = __float_as_uint(x);
  return (unsigned short)((u + 0x7FFFu + ((u >> 16) & 1u)) >> 16);  // RNE
}
static __device__ __forceinline__ unsigned int pk2(float a, float b) {
  return (unsigned int)f2bf(a) | ((unsigned int)f2bf(b) << 16);
}

// LDS-only barrier (drains lgkmcnt, NOT vmcnt): global prefetch loads stay in
// flight across it. All cross-wave data flows through LDS.
static __device__ __forceinline__ void barrier_lds() {
  __builtin_amdgcn_sched_barrier(0);
  asm volatile("s_waitcnt lgkmcnt(0)" ::: "memory");
  __builtin_amdgcn_s_barrier();
  __builtin_amdgcn_sched_barrier(0);
}

// k-slot permutation pi: slot m=8g+u holds l = 4g+u (u<4) or 16+4g+(u-4)
// (u>=4) within each 32-l pair; makes the mtile MFMA output order directly
// usable as an A-fragment (M never touches LDS). X^T and (dec*B)^T staged
// with the SAME permutation (MFMA invariant to consistent k-permute).
static __device__ __forceinline__ int invperm(int l) {
  const int jp = l >> 5, v = l & 31;
  return jp * 32 + (v < 16 ? (((v >> 2) << 3) | (v & 3))
                           : ((((v - 16) >> 2) << 3) | 4 | ((v - 16) & 3)));
}

// One block per (b,h), 8 waves, 32 sequential chunks, ONE barrier per chunk.
// Wave pair (2k,2k+1) owns l-block k (redundant M-frag build); each wave does
// 2 p-blocks of Y; waves 0-3 also do one p-block of the S/ST update.
// Staging double-buffered so stage(c+1) overlaps compute(c) in one window.
__global__ __launch_bounds__(512) void ssd_fused(
    const float* __restrict__ Xg, const float* __restrict__ Ag,
    const float* __restrict__ Bg, const float* __restrict__ Cg,
    float* __restrict__ Yg) {
  const int h = blockIdx.x & (NH - 1);
  const int b = blockIdx.x >> 4;
  const int t = threadIdx.x;
  const int w = t >> 6;
  const int lane = t & 63;
  const int g = lane >> 4;
  const int cc = lane & 15;

  __shared__ __align__(16) unsigned short sXt[2][PD][64];       // X^T permuted
  __shared__ __align__(16) unsigned short sB[2][LB][ND + 8];
  __shared__ __align__(16) unsigned short sC[2][LB][ND + 8];    // C' = e_l*C
  __shared__ __align__(16) unsigned short sBdT[2][ND][LB + 8];  // (dec*B)^T perm
  __shared__ __align__(16) float sSTf[2][PD][ND + 4];           // ST fp32 ping-pong
  __shared__ __align__(16) unsigned short sSTb[2][PD][ND + 8];  // ST bf16 mirror
  __shared__ float sER[NC][LB];   // exp(+acs)
  __shared__ float sRR[NC][LB];   // exp(-acs)
  __shared__ float sEtot[NC];

  // ---- prologue: decay tables for ALL chunks ----
  {
    float av[4];
#pragma unroll
    for (int k = 0; k < 4; ++k)
      av[k] = Ag[((size_t)(b * SEQL + (w + 8 * k) * LB + lane)) * NH + h];
#pragma unroll
    for (int k = 0; k < 4; ++k) {
      const int c = w + 8 * k;
      float v = av[k];
#pragma unroll
      for (int d = 1; d < 64; d <<= 1) {
        float o = __shfl_up(v, d, 64);
        if (lane >= d) v += o;
      }
      const float e = expf(v);
      sER[c][lane] = e;
      sRR[c][lane] = expf(-v);
      if (lane == 63) sEtot[c] = e;
    }
  }
  for (int i = t; i < PD * (ND + 4); i += 512) ((float*)sSTf[0])[i] = 0.f;
  for (int i = t; i < PD * (ND + 8); i += 512) ((unsigned short*)sSTb[0])[i] = 0;

  // thread maps
  const int xl0 = (t >> 4) * 2, xp0 = (t & 15) * 4;  // X: 2 l x 4 p
  const int bl = t >> 3, bn0 = (t & 7) * 2;          // B/C: 1 row x 2 n
  const int n_bt = t >> 5, l_bt = (t & 31) * 2;      // BdT: 1 n x 2 l
  const int mX = invperm(xl0);
  const int mB = invperm(l_bt);
  const int mB1 = invperm(l_bt + 1);
  float4 px0, px1;
  float2 pb2, pc2;
  float pbA_v, pbB_v;

#define PREF(ci) do { \
    const size_t s0_ = (size_t)(b * SEQL + (ci) * LB); \
    px0 = *(const float4*)&Xg[(s0_ + xl0) * NHP + h * PD + xp0]; \
    px1 = *(const float4*)&Xg[(s0_ + xl0 + 1) * NHP + h * PD + xp0]; \
    pb2 = *(const float2*)&Bg[(s0_ + bl) * NHN + h * ND + bn0]; \
    pc2 = *(const float2*)&Cg[(s0_ + bl) * NHN + h * ND + bn0]; \
    pbA_v = Bg[(s0_ + l_bt) * NHN + h * ND + n_bt]; \
    pbB_v = Bg[(s0_ + l_bt + 1) * NHN + h * ND + n_bt]; \
  } while (0)

#define STAGE(bufi, ci) do { \
    _Pragma("unroll") \
    for (int j_ = 0; j_ < 4; ++j_) { \
      const int p_ = xp0 + j_; \
      const int mm_ = ((((mX >> 3) ^ ((p_ >> 3) & 7)) << 3) | (mX & 7)); \
      *(unsigned int*)&sXt[bufi][p_][mm_] = pk2((&px0.x)[j_], (&px1.x)[j_]); \
    } \
    { const float el_ = sER[ci][bl]; \
      *(unsigned int*)&sB[bufi][bl][bn0] = pk2(pb2.x, pb2.y); \
      *(unsigned int*)&sC[bufi][bl][bn0] = pk2(el_ * pc2.x, el_ * pc2.y); } \
    { const float et_ = sEtot[ci]; \
      sBdT[bufi][n_bt][mB]  = f2bf(et_ * sRR[ci][l_bt] * pbA_v); \
      sBdT[bufi][n_bt][mB1] = f2bf(et_ * sRR[ci][l_bt + 1] * pbB_v); } \
  } while (0)

  const bf16x8 zf8 = {0, 0, 0, 0, 0, 0, 0, 0};
  auto xfrag = [&](int buf, int p_, int kb) -> bf16x8 {
    return *(const bf16x8*)&sXt[buf][p_][(kb ^ ((p_ >> 3) & 7)) << 3];
  };

  __syncthreads();  // tables + ST init visible before STAGE reads them

  PREF(0);
  STAGE(0, 0);
  PREF(1);
  barrier_lds();  // stage(0) visible

  const int lb = w >> 1;            // l-block owned by this wave's pair
  const int pb0 = (w & 1) * 2;      // first of two Y p-blocks
  const int l = lb * 16 + cc;

  for (int c = 0; c < NC; ++c) {
    const int db = c & 1, nb = db ^ 1;

    // ---- M-frags in registers (redundant within wave pair) ----
    bf16x8 cf = zf8;
    if (g < 2) cf = *(const bf16x8*)&sC[db][l][g * 8];
    auto mtile = [&](int sb, bool mask) -> uint2 {
      bf16x8 bfr = zf8;
      if (g < 2) bfr = *(const bf16x8*)&sB[db][sb * 16 + cc][g * 8];
      f32x4 z4 = {0.f, 0.f, 0.f, 0.f};
      f32x4 d = __builtin_amdgcn_mfma_f32_16x16x32_bf16(bfr, cf, z4, 0, 0, 0);
      // lane holds D'[s = sb*16+4g+r][l]
      float m[4];
#pragma unroll
      for (int r = 0; r < 4; ++r) {
        m[r] = d[r] * sRR[c][sb * 16 + 4 * g + r];
        if (mask && (4 * g + r) > cc) m[r] = 0.f;
      }
      return make_uint2(pk2(m[0], m[1]), pk2(m[2], m[3]));
    };
    union { bf16x8 v; unsigned int u[4]; } mf0, mf1;
    mf0.u[0] = mf0.u[1] = mf0.u[2] = mf0.u[3] = 0u;
    mf1.u[0] = mf1.u[1] = mf1.u[2] = mf1.u[3] = 0u;
    if (lb == 0) {
      const uint2 t0 = mtile(0, true);
      mf0.u[0] = t0.x; mf0.u[1] = t0.y;
    } else if (lb == 1) {
      const uint2 t0 = mtile(0, false), t1 = mtile(1, true);
      mf0.u[0] = t0.x; mf0.u[1] = t0.y; mf0.u[2] = t1.x; mf0.u[3] = t1.y;
    } else if (lb == 2) {
      const uint2 t0 = mtile(0, false), t1 = mtile(1, false), t2 = mtile(2, true);
      mf0.u[0] = t0.x; mf0.u[1] = t0.y; mf0.u[2] = t1.x; mf0.u[3] = t1.y;
      mf1.u[0] = t2.x; mf1.u[1] = t2.y;
    } else {
      const uint2 t0 = mtile(0, false), t1 = mtile(1, false);
      const uint2 t2 = mtile(2, false), t3 = mtile(3, true);
      mf0.u[0] = t0.x; mf0.u[1] = t0.y; mf0.u[2] = t1.x; mf0.u[3] = t1.y;
      mf1.u[0] = t2.x; mf1.u[1] = t2.y; mf1.u[2] = t3.x; mf1.u[3] = t3.y;
    }

    // ---- Y tiles: 2 p-blocks per wave ----
#pragma unroll
    for (int pbi = 0; pbi < 2; ++pbi) {
      const int p = (pb0 + pbi) * 16 + cc;
      bf16x8 stf = zf8;
      if (g < 2) stf = *(const bf16x8*)&sSTb[db][p][g * 8];
      f32x4 acc = {0.f, 0.f, 0.f, 0.f};
      acc = __builtin_amdgcn_mfma_f32_16x16x32_bf16(cf, stf, acc, 0, 0, 0);
      acc = __builtin_amdgcn_mfma_f32_16x16x32_bf16(mf0.v, xfrag(db, p, g), acc, 0, 0, 0);
      if (lb >= 2)
        acc = __builtin_amdgcn_mfma_f32_16x16x32_bf16(mf1.v, xfrag(db, p, 4 + g), acc, 0, 0, 0);
      const size_t yb =
          ((size_t)(b * SEQL + c * LB + lb * 16 + 4 * g)) * NHP + h * PD + p;
#pragma unroll
      for (int r = 0; r < 4; ++r) Yg[yb + (size_t)r * NHP] = acc[r];
    }

    // ---- S/ST update on the light waves (0-3), one p-block each ----
    if (w < 4) {
      const int pS = w * 16 + cc;
      bf16x8 ad0 = *(const bf16x8*)&sBdT[db][cc][g * 8];
      bf16x8 ad1 = *(const bf16x8*)&sBdT[db][cc][32 + g * 8];
      f32x4 s4 = {0.f, 0.f, 0.f, 0.f};
      s4 = __builtin_amdgcn_mfma_f32_16x16x32_bf16(ad0, xfrag(db, pS, g), s4, 0, 0, 0);
      s4 = __builtin_amdgcn_mfma_f32_16x16x32_bf16(ad1, xfrag(db, pS, 4 + g), s4, 0, 0, 0);
      const float etot = sEtot[c];
      // lane holds S[n = 4g+r][pS]
      float4 old = *(const float4*)&sSTf[db][pS][4 * g];
      float4 nw;
      nw.x = old.x * etot + s4[0];
      nw.y = old.y * etot + s4[1];
      nw.z = old.z * etot + s4[2];
      nw.w = old.w * etot + s4[3];
      *(float4*)&sSTf[nb][pS][4 * g] = nw;
      uint2 ub;
      ub.x = pk2(nw.x, nw.y);
      ub.y = pk2(nw.z, nw.w);
      *(uint2*)&sSTb[nb][pS][4 * g] = ub;
    }

    // ---- stage chunk c+1 into buf nb (overlaps compute above) ----
    if (c + 1 < NC) {
      STAGE(nb, c + 1);
      if (c + 2 < NC) PREF(c + 2);
    }
    barrier_lds();  // end of window: staged data + ST[nb] visible
  }
#undef PREF
#undef STAGE
}

extern "C" void kernel_launch(void* const* d_in, const int* in_sizes, int n_in,
                              void* d_out, int out_size, void* d_ws, size_t ws_size,
                              hipStream_t stream) {
  (void)in_sizes; (void)n_in; (void)out_size; (void)d_ws; (void)ws_size;
  const float* X = (const float*)d_in[0];
  const float* A = (const float*)d_in[1];
  const float* B = (const float*)d_in[2];
  const float* C = (const float*)d_in[3];
  float* Y = (float*)d_out;
  ssd_fused<<<BS * NH, 512, 0, stream>>>(X, A, B, C, Y);
}

// Round 15
// 79.106 us; speedup vs baseline: 1.3856x; 1.0733x over previous
//
#include <hip/hip_runtime.h>

#define BS 16
#define SEQL 2048
#define NH 16
#define PD 64
#define ND 16
#define LB 64
#define NC 32          // SEQL / LB
#define NHP (NH * PD)  // 1024
#define NHN (NH * ND)  // 256

typedef __attribute__((ext_vector_type(8))) short bf16x8;
typedef __attribute__((ext_vector_type(4))) float f32x4;

static __device__ __forceinline__ unsigned short f2bf(float x) {
  unsigned int u = __float_as_uint(x);
  return (unsigned short)((u + 0x7FFFu + ((u >> 16) & 1u)) >> 16);  // RNE
}
static __device__ __forceinline__ unsigned int pk2(float a, float b) {
  return (unsigned int)f2bf(a) | ((unsigned int)f2bf(b) << 16);
}

// LDS-only barrier (drains lgkmcnt, NOT vmcnt): global prefetch loads stay in
// flight across it. All cross-wave data flows through LDS.
static __device__ __forceinline__ void barrier_lds() {
  __builtin_amdgcn_sched_barrier(0);
  asm volatile("s_waitcnt lgkmcnt(0)" ::: "memory");
  __builtin_amdgcn_s_barrier();
  __builtin_amdgcn_sched_barrier(0);
}

// k-slot permutation pi: slot m=8g+u holds l = 4g+u (u<4) or 16+4g+(u-4)
// (u>=4) within each 32-l pair; makes the mtile MFMA output order directly
// usable as an A-fragment (M never touches LDS). X^T and (dec*B)^T staged
// with the SAME permutation (MFMA invariant to consistent k-permute).
static __device__ __forceinline__ int invperm(int l) {
  const int jp = l >> 5, v = l & 31;
  return jp * 32 + (v < 16 ? (((v >> 2) << 3) | (v & 3))
                           : ((((v - 16) >> 2) << 3) | 4 | ((v - 16) & 3)));
}

// One block per (b,h), 8 waves, 32 sequential chunks, ONE barrier per chunk.
// Wave pair (2k,2k+1) owns l-block k (redundant M-frag build); each wave does
// 2 p-blocks of Y; waves 0-3 also do one p-block of the S/ST update.
// Staging double-buffered so stage(c+1) overlaps compute(c) in one window.
// (Faithful R9 kernel + prologue __syncthreads race fix.)
__global__ __launch_bounds__(512) void ssd_fused(
    const float* __restrict__ Xg, const float* __restrict__ Ag,
    const float* __restrict__ Bg, const float* __restrict__ Cg,
    float* __restrict__ Yg) {
  const int h = blockIdx.x & (NH - 1);
  const int b = blockIdx.x >> 4;
  const int t = threadIdx.x;
  const int w = t >> 6;
  const int lane = t & 63;
  const int g = lane >> 4;
  const int cc = lane & 15;

  __shared__ __align__(16) unsigned short sXt[2][PD][64];       // X^T permuted
  __shared__ __align__(16) unsigned short sB[2][LB][ND + 8];
  __shared__ __align__(16) unsigned short sC[2][LB][ND + 8];    // C' = e_l*C
  __shared__ __align__(16) unsigned short sBdT[2][ND][LB + 8];  // (dec*B)^T perm
  __shared__ __align__(16) float sSTf[2][PD][ND + 4];           // ST fp32 ping-pong
  __shared__ __align__(16) unsigned short sSTb[2][PD][ND + 8];  // ST bf16 mirror
  __shared__ float sER[NC][LB];   // exp(+acs)
  __shared__ float sRR[NC][LB];   // exp(-acs)
  __shared__ float sEtot[NC];

  // ---- prologue: decay tables for ALL chunks ----
  {
    float av[4];
#pragma unroll
    for (int k = 0; k < 4; ++k)
      av[k] = Ag[((size_t)(b * SEQL + (w + 8 * k) * LB + lane)) * NH + h];
#pragma unroll
    for (int k = 0; k < 4; ++k) {
      const int c = w + 8 * k;
      float v = av[k];
#pragma unroll
      for (int d = 1; d < 64; d <<= 1) {
        float o = __shfl_up(v, d, 64);
        if (lane >= d) v += o;
      }
      const float e = expf(v);
      sER[c][lane] = e;
      sRR[c][lane] = expf(-v);
      if (lane == 63) sEtot[c] = e;
    }
  }
  for (int i = t; i < PD * (ND + 4); i += 512) ((float*)sSTf[0])[i] = 0.f;
  for (int i = t; i < PD * (ND + 8); i += 512) ((unsigned short*)sSTb[0])[i] = 0;
  __syncthreads();  // RACE FIX: tables + ST init visible BEFORE STAGE(0,0)
                    // reads sER/sRR/sEtot written by other waves.

  // thread maps
  const int xl0 = (t >> 4) * 2, xp0 = (t & 15) * 4;  // X: 2 l x 4 p
  const int bl = t >> 3, bn0 = (t & 7) * 2;          // B/C: 1 row x 2 n
  const int mX = invperm(xl0);
  const int mB = invperm(bl);
  float4 px0, px1;
  float2 pb2, pc2;

#define PREF(ci) do { \
    const size_t s0_ = (size_t)(b * SEQL + (ci) * LB); \
    px0 = *(const float4*)&Xg[(s0_ + xl0) * NHP + h * PD + xp0]; \
    px1 = *(const float4*)&Xg[(s0_ + xl0 + 1) * NHP + h * PD + xp0]; \
    pb2 = *(const float2*)&Bg[(s0_ + bl) * NHN + h * ND + bn0]; \
    pc2 = *(const float2*)&Cg[(s0_ + bl) * NHN + h * ND + bn0]; \
  } while (0)

#define STAGE(bufi, ci) do { \
    _Pragma("unroll") \
    for (int j_ = 0; j_ < 4; ++j_) { \
      const int p_ = xp0 + j_; \
      const int mm_ = ((((mX >> 3) ^ ((p_ >> 3) & 7)) << 3) | (mX & 7)); \
      *(unsigned int*)&sXt[bufi][p_][mm_] = pk2((&px0.x)[j_], (&px1.x)[j_]); \
    } \
    { const float el_ = sER[ci][bl]; \
      const float dl_ = sEtot[ci] * sRR[ci][bl]; \
      *(unsigned int*)&sB[bufi][bl][bn0] = pk2(pb2.x, pb2.y); \
      *(unsigned int*)&sC[bufi][bl][bn0] = pk2(el_ * pc2.x, el_ * pc2.y); \
      sBdT[bufi][bn0][mB] = f2bf(dl_ * pb2.x); \
      sBdT[bufi][bn0 + 1][mB] = f2bf(dl_ * pb2.y); } \
  } while (0)

  const bf16x8 zf8 = {0, 0, 0, 0, 0, 0, 0, 0};
  auto xfrag = [&](int buf, int p_, int kb) -> bf16x8 {
    return *(const bf16x8*)&sXt[buf][p_][(kb ^ ((p_ >> 3) & 7)) << 3];
  };

  PREF(0);
  STAGE(0, 0);
  PREF(1);
  barrier_lds();  // stage(0) visible

  const int lb = w >> 1;            // l-block owned by this wave's pair
  const int pb0 = (w & 1) * 2;      // first of two Y p-blocks
  const int l = lb * 16 + cc;

  for (int c = 0; c < NC; ++c) {
    const int db = c & 1, nb = db ^ 1;

    // ---- M-frags in registers (redundant within wave pair) ----
    bf16x8 cf = zf8;
    if (g < 2) cf = *(const bf16x8*)&sC[db][l][g * 8];
    auto mtile = [&](int sb, bool mask) -> uint2 {
      bf16x8 bfr = zf8;
      if (g < 2) bfr = *(const bf16x8*)&sB[db][sb * 16 + cc][g * 8];
      f32x4 z4 = {0.f, 0.f, 0.f, 0.f};
      f32x4 d = __builtin_amdgcn_mfma_f32_16x16x32_bf16(bfr, cf, z4, 0, 0, 0);
      // lane holds D'[s = sb*16+4g+r][l]
      float m[4];
#pragma unroll
      for (int r = 0; r < 4; ++r) {
        m[r] = d[r] * sRR[c][sb * 16 + 4 * g + r];
        if (mask && (4 * g + r) > cc) m[r] = 0.f;
      }
      return make_uint2(pk2(m[0], m[1]), pk2(m[2], m[3]));
    };
    union { bf16x8 v; unsigned int u[4]; } mf0, mf1;
    mf0.u[0] = mf0.u[1] = mf0.u[2] = mf0.u[3] = 0u;
    mf1.u[0] = mf1.u[1] = mf1.u[2] = mf1.u[3] = 0u;
    if (lb == 0) {
      const uint2 t0 = mtile(0, true);
      mf0.u[0] = t0.x; mf0.u[1] = t0.y;
    } else if (lb == 1) {
      const uint2 t0 = mtile(0, false), t1 = mtile(1, true);
      mf0.u[0] = t0.x; mf0.u[1] = t0.y; mf0.u[2] = t1.x; mf0.u[3] = t1.y;
    } else if (lb == 2) {
      const uint2 t0 = mtile(0, false), t1 = mtile(1, false), t2 = mtile(2, true);
      mf0.u[0] = t0.x; mf0.u[1] = t0.y; mf0.u[2] = t1.x; mf0.u[3] = t1.y;
      mf1.u[0] = t2.x; mf1.u[1] = t2.y;
    } else {
      const uint2 t0 = mtile(0, false), t1 = mtile(1, false);
      const uint2 t2 = mtile(2, false), t3 = mtile(3, true);
      mf0.u[0] = t0.x; mf0.u[1] = t0.y; mf0.u[2] = t1.x; mf0.u[3] = t1.y;
      mf1.u[0] = t2.x; mf1.u[1] = t2.y; mf1.u[2] = t3.x; mf1.u[3] = t3.y;
    }

    // ---- Y tiles: 2 p-blocks per wave ----
#pragma unroll
    for (int pbi = 0; pbi < 2; ++pbi) {
      const int p = (pb0 + pbi) * 16 + cc;
      bf16x8 stf = zf8;
      if (g < 2) stf = *(const bf16x8*)&sSTb[db][p][g * 8];
      f32x4 acc = {0.f, 0.f, 0.f, 0.f};
      acc = __builtin_amdgcn_mfma_f32_16x16x32_bf16(cf, stf, acc, 0, 0, 0);
      acc = __builtin_amdgcn_mfma_f32_16x16x32_bf16(mf0.v, xfrag(db, p, g), acc, 0, 0, 0);
      if (lb >= 2)
        acc = __builtin_amdgcn_mfma_f32_16x16x32_bf16(mf1.v, xfrag(db, p, 4 + g), acc, 0, 0, 0);
      const size_t yb =
          ((size_t)(b * SEQL + c * LB + lb * 16 + 4 * g)) * NHP + h * PD + p;
#pragma unroll
      for (int r = 0; r < 4; ++r) Yg[yb + (size_t)r * NHP] = acc[r];
    }

    // ---- S/ST update on the light waves (0-3), one p-block each ----
    if (w < 4) {
      const int pS = w * 16 + cc;
      bf16x8 ad0 = *(const bf16x8*)&sBdT[db][cc][g * 8];
      bf16x8 ad1 = *(const bf16x8*)&sBdT[db][cc][32 + g * 8];
      f32x4 s4 = {0.f, 0.f, 0.f, 0.f};
      s4 = __builtin_amdgcn_mfma_f32_16x16x32_bf16(ad0, xfrag(db, pS, g), s4, 0, 0, 0);
      s4 = __builtin_amdgcn_mfma_f32_16x16x32_bf16(ad1, xfrag(db, pS, 4 + g), s4, 0, 0, 0);
      const float etot = sEtot[c];
      // lane holds S[n = 4g+r][pS]
      float4 old = *(const float4*)&sSTf[db][pS][4 * g];
      float4 nw;
      nw.x = old.x * etot + s4[0];
      nw.y = old.y * etot + s4[1];
      nw.z = old.z * etot + s4[2];
      nw.w = old.w * etot + s4[3];
      *(float4*)&sSTf[nb][pS][4 * g] = nw;
      uint2 ub;
      ub.x = pk2(nw.x, nw.y);
      ub.y = pk2(nw.z, nw.w);
      *(uint2*)&sSTb[nb][pS][4 * g] = ub;
    }

    // ---- stage chunk c+1 into buf nb (overlaps compute above) ----
    if (c + 1 < NC) {
      STAGE(nb, c + 1);
      if (c + 2 < NC) PREF(c + 2);
    }
    barrier_lds();  // end of window: staged data + ST[nb] visible
  }
#undef PREF
#undef STAGE
}

extern "C" void kernel_launch(void* const* d_in, const int* in_sizes, int n_in,
                              void* d_out, int out_size, void* d_ws, size_t ws_size,
                              hipStream_t stream) {
  (void)in_sizes; (void)n_in; (void)out_size; (void)d_ws; (void)ws_size;
  const float* X = (const float*)d_in[0];
  const float* A = (const float*)d_in[1];
  const float* B = (const float*)d_in[2];
  const float* C = (const float*)d_in[3];
  float* Y = (float*)d_out;
  ssd_fused<<<BS * NH, 512, 0, stream>>>(X, A, B, C, Y);
}

// Round 16
// 78.397 us; speedup vs baseline: 1.3981x; 1.0090x over previous
//
#include <hip/hip_runtime.h>

#define BS 16
#define SEQL 2048
#define NH 16
#define PD 64
#define ND 16
#define LB 64
#define NC 32          // SEQL / LB
#define NHP (NH * PD)  // 1024
#define NHN (NH * ND)  // 256

typedef __attribute__((ext_vector_type(8))) short bf16x8;
typedef __attribute__((ext_vector_type(4))) float f32x4;

static __device__ __forceinline__ unsigned short f2bf(float x) {
  unsigned int u = __float_as_uint(x);
  return (unsigned short)((u + 0x7FFFu + ((u >> 16) & 1u)) >> 16);  // RNE
}
static __device__ __forceinline__ unsigned int pk2(float a, float b) {
  return (unsigned int)f2bf(a) | ((unsigned int)f2bf(b) << 16);
}

// LDS-only barrier (drains lgkmcnt, NOT vmcnt): global prefetch loads stay in
// flight across it. All cross-wave data flows through LDS.
static __device__ __forceinline__ void barrier_lds() {
  __builtin_amdgcn_sched_barrier(0);
  asm volatile("s_waitcnt lgkmcnt(0)" ::: "memory");
  __builtin_amdgcn_s_barrier();
  __builtin_amdgcn_sched_barrier(0);
}

// k-slot permutation pi: slot m=8g+u holds l = 4g+u (u<4) or 16+4g+(u-4)
// (u>=4) within each 32-l pair; makes the mtile MFMA output order directly
// usable as an A-fragment (M never touches LDS). X^T and (dec*B)^T staged
// with the SAME permutation (MFMA invariant to consistent k-permute).
static __device__ __forceinline__ int invperm(int l) {
  const int jp = l >> 5, v = l & 31;
  return jp * 32 + (v < 16 ? (((v >> 2) << 3) | (v & 3))
                           : ((((v - 16) >> 2) << 3) | 4 | ((v - 16) & 3)));
}

// One block per (b,h), 8 waves, 32 sequential chunks, ONE barrier per chunk.
// Wave pair (2k,2k+1) owns l-block k (redundant M-frag build); each wave does
// 2 p-blocks of Y; waves 0-3 also do one p-block of the S/ST update.
// sXt swizzle keyed on p&7: xfrag reads (lanes span p&7 = 0..7) become 2-way
// conflict-free; 128B rows otherwise put all 16 lanes on the same bank group.
__global__ __launch_bounds__(512) void ssd_fused(
    const float* __restrict__ Xg, const float* __restrict__ Ag,
    const float* __restrict__ Bg, const float* __restrict__ Cg,
    float* __restrict__ Yg) {
  const int h = blockIdx.x & (NH - 1);
  const int b = blockIdx.x >> 4;
  const int t = threadIdx.x;
  const int w = t >> 6;
  const int lane = t & 63;
  const int g = lane >> 4;
  const int cc = lane & 15;

  __shared__ __align__(16) unsigned short sXt[2][PD][64];       // X^T permuted
  __shared__ __align__(16) unsigned short sB[2][LB][ND + 8];
  __shared__ __align__(16) unsigned short sC[2][LB][ND + 8];    // C' = e_l*C
  __shared__ __align__(16) unsigned short sBdT[2][ND][LB + 8];  // (dec*B)^T perm
  __shared__ __align__(16) float sSTf[2][PD][ND + 4];           // ST fp32 ping-pong
  __shared__ __align__(16) unsigned short sSTb[2][PD][ND + 8];  // ST bf16 mirror
  __shared__ float sER[NC][LB];   // exp(+acs)
  __shared__ float sRR[NC][LB];   // exp(-acs)
  __shared__ float sEtot[NC];

  // ---- prologue: decay tables for ALL chunks ----
  {
    float av[4];
#pragma unroll
    for (int k = 0; k < 4; ++k)
      av[k] = Ag[((size_t)(b * SEQL + (w + 8 * k) * LB + lane)) * NH + h];
#pragma unroll
    for (int k = 0; k < 4; ++k) {
      const int c = w + 8 * k;
      float v = av[k];
#pragma unroll
      for (int d = 1; d < 64; d <<= 1) {
        float o = __shfl_up(v, d, 64);
        if (lane >= d) v += o;
      }
      const float e = expf(v);
      sER[c][lane] = e;
      sRR[c][lane] = expf(-v);
      if (lane == 63) sEtot[c] = e;
    }
  }
  for (int i = t; i < PD * (ND + 4); i += 512) ((float*)sSTf[0])[i] = 0.f;
  for (int i = t; i < PD * (ND + 8); i += 512) ((unsigned short*)sSTb[0])[i] = 0;
  __syncthreads();  // RACE FIX: tables + ST init visible BEFORE STAGE(0,0)
                    // reads sER/sRR/sEtot written by other waves.

  // thread maps
  const int xl0 = (t >> 4) * 2, xp0 = (t & 15) * 4;  // X: 2 l x 4 p
  const int bl = t >> 3, bn0 = (t & 7) * 2;          // B/C: 1 row x 2 n
  const int mX = invperm(xl0);
  const int mB = invperm(bl);
  float4 px0, px1;
  float2 pb2, pc2;

#define PREF(ci) do { \
    const size_t s0_ = (size_t)(b * SEQL + (ci) * LB); \
    px0 = *(const float4*)&Xg[(s0_ + xl0) * NHP + h * PD + xp0]; \
    px1 = *(const float4*)&Xg[(s0_ + xl0 + 1) * NHP + h * PD + xp0]; \
    pb2 = *(const float2*)&Bg[(s0_ + bl) * NHN + h * ND + bn0]; \
    pc2 = *(const float2*)&Cg[(s0_ + bl) * NHN + h * ND + bn0]; \
  } while (0)

#define STAGE(bufi, ci) do { \
    _Pragma("unroll") \
    for (int j_ = 0; j_ < 4; ++j_) { \
      const int p_ = xp0 + j_; \
      const int mm_ = ((((mX >> 3) ^ (p_ & 7)) << 3) | (mX & 7)); \
      *(unsigned int*)&sXt[bufi][p_][mm_] = pk2((&px0.x)[j_], (&px1.x)[j_]); \
    } \
    { const float el_ = sER[ci][bl]; \
      const float dl_ = sEtot[ci] * sRR[ci][bl]; \
      *(unsigned int*)&sB[bufi][bl][bn0] = pk2(pb2.x, pb2.y); \
      *(unsigned int*)&sC[bufi][bl][bn0] = pk2(el_ * pc2.x, el_ * pc2.y); \
      sBdT[bufi][bn0][mB] = f2bf(dl_ * pb2.x); \
      sBdT[bufi][bn0 + 1][mB] = f2bf(dl_ * pb2.y); } \
  } while (0)

  const bf16x8 zf8 = {0, 0, 0, 0, 0, 0, 0, 0};
  auto xfrag = [&](int buf, int p_, int kb) -> bf16x8 {
    return *(const bf16x8*)&sXt[buf][p_][(kb ^ (p_ & 7)) << 3];
  };

  PREF(0);
  STAGE(0, 0);
  PREF(1);
  barrier_lds();  // stage(0) visible

  const int lb = w >> 1;            // l-block owned by this wave's pair
  const int pb0 = (w & 1) * 2;      // first of two Y p-blocks
  const int l = lb * 16 + cc;

  for (int c = 0; c < NC; ++c) {
    const int db = c & 1, nb = db ^ 1;

    // ---- M-frags in registers (redundant within wave pair) ----
    bf16x8 cf = zf8;
    if (g < 2) cf = *(const bf16x8*)&sC[db][l][g * 8];
    auto mtile = [&](int sb, bool mask) -> uint2 {
      bf16x8 bfr = zf8;
      if (g < 2) bfr = *(const bf16x8*)&sB[db][sb * 16 + cc][g * 8];
      f32x4 z4 = {0.f, 0.f, 0.f, 0.f};
      f32x4 d = __builtin_amdgcn_mfma_f32_16x16x32_bf16(bfr, cf, z4, 0, 0, 0);
      // lane holds D'[s = sb*16+4g+r][l]
      float m[4];
#pragma unroll
      for (int r = 0; r < 4; ++r) {
        m[r] = d[r] * sRR[c][sb * 16 + 4 * g + r];
        if (mask && (4 * g + r) > cc) m[r] = 0.f;
      }
      return make_uint2(pk2(m[0], m[1]), pk2(m[2], m[3]));
    };
    union { bf16x8 v; unsigned int u[4]; } mf0, mf1;
    mf0.u[0] = mf0.u[1] = mf0.u[2] = mf0.u[3] = 0u;
    mf1.u[0] = mf1.u[1] = mf1.u[2] = mf1.u[3] = 0u;
    if (lb == 0) {
      const uint2 t0 = mtile(0, true);
      mf0.u[0] = t0.x; mf0.u[1] = t0.y;
    } else if (lb == 1) {
      const uint2 t0 = mtile(0, false), t1 = mtile(1, true);
      mf0.u[0] = t0.x; mf0.u[1] = t0.y; mf0.u[2] = t1.x; mf0.u[3] = t1.y;
    } else if (lb == 2) {
      const uint2 t0 = mtile(0, false), t1 = mtile(1, false), t2 = mtile(2, true);
      mf0.u[0] = t0.x; mf0.u[1] = t0.y; mf0.u[2] = t1.x; mf0.u[3] = t1.y;
      mf1.u[0] = t2.x; mf1.u[1] = t2.y;
    } else {
      const uint2 t0 = mtile(0, false), t1 = mtile(1, false);
      const uint2 t2 = mtile(2, false), t3 = mtile(3, true);
      mf0.u[0] = t0.x; mf0.u[1] = t0.y; mf0.u[2] = t1.x; mf0.u[3] = t1.y;
      mf1.u[0] = t2.x; mf1.u[1] = t2.y; mf1.u[2] = t3.x; mf1.u[3] = t3.y;
    }

    // ---- Y tiles: 2 p-blocks per wave ----
#pragma unroll
    for (int pbi = 0; pbi < 2; ++pbi) {
      const int p = (pb0 + pbi) * 16 + cc;
      bf16x8 stf = zf8;
      if (g < 2) stf = *(const bf16x8*)&sSTb[db][p][g * 8];
      f32x4 acc = {0.f, 0.f, 0.f, 0.f};
      acc = __builtin_amdgcn_mfma_f32_16x16x32_bf16(cf, stf, acc, 0, 0, 0);
      acc = __builtin_amdgcn_mfma_f32_16x16x32_bf16(mf0.v, xfrag(db, p, g), acc, 0, 0, 0);
      if (lb >= 2)
        acc = __builtin_amdgcn_mfma_f32_16x16x32_bf16(mf1.v, xfrag(db, p, 4 + g), acc, 0, 0, 0);
      const size_t yb =
          ((size_t)(b * SEQL + c * LB + lb * 16 + 4 * g)) * NHP + h * PD + p;
#pragma unroll
      for (int r = 0; r < 4; ++r) Yg[yb + (size_t)r * NHP] = acc[r];
    }

    // ---- S/ST update on the light waves (0-3), one p-block each ----
    if (w < 4) {
      const int pS = w * 16 + cc;
      bf16x8 ad0 = *(const bf16x8*)&sBdT[db][cc][g * 8];
      bf16x8 ad1 = *(const bf16x8*)&sBdT[db][cc][32 + g * 8];
      f32x4 s4 = {0.f, 0.f, 0.f, 0.f};
      s4 = __builtin_amdgcn_mfma_f32_16x16x32_bf16(ad0, xfrag(db, pS, g), s4, 0, 0, 0);
      s4 = __builtin_amdgcn_mfma_f32_16x16x32_bf16(ad1, xfrag(db, pS, 4 + g), s4, 0, 0, 0);
      const float etot = sEtot[c];
      // lane holds S[n = 4g+r][pS]
      float4 old = *(const float4*)&sSTf[db][pS][4 * g];
      float4 nw;
      nw.x = old.x * etot + s4[0];
      nw.y = old.y * etot + s4[1];
      nw.z = old.z * etot + s4[2];
      nw.w = old.w * etot + s4[3];
      *(float4*)&sSTf[nb][pS][4 * g] = nw;
      uint2 ub;
      ub.x = pk2(nw.x, nw.y);
      ub.y = pk2(nw.z, nw.w);
      *(uint2*)&sSTb[nb][pS][4 * g] = ub;
    }

    // ---- stage chunk c+1 into buf nb (overlaps compute above) ----
    if (c + 1 < NC) {
      STAGE(nb, c + 1);
      if (c + 2 < NC) PREF(c + 2);
    }
    barrier_lds();  // end of window: staged data + ST[nb] visible
  }
#undef PREF
#undef STAGE
}

extern "C" void kernel_launch(void* const* d_in, const int* in_sizes, int n_in,
                              void* d_out, int out_size, void* d_ws, size_t ws_size,
                              hipStream_t stream) {
  (void)in_sizes; (void)n_in; (void)out_size; (void)d_ws; (void)ws_size;
  const float* X = (const float*)d_in[0];
  const float* A = (const float*)d_in[1];
  const float* B = (const float*)d_in[2];
  const float* C = (const float*)d_in[3];
  float* Y = (float*)d_out;
  ssd_fused<<<BS * NH, 512, 0, stream>>>(X, A, B, C, Y);
}

// Round 17
// 77.901 us; speedup vs baseline: 1.4070x; 1.0064x over previous
//
#include <hip/hip_runtime.h>

#define BS 16
#define SEQL 2048
#define NH 16
#define PD 64
#define ND 16
#define LB 64
#define NC 32          // SEQL / LB
#define NHP (NH * PD)  // 1024
#define NHN (NH * ND)  // 256

typedef __attribute__((ext_vector_type(8))) short bf16x8;
typedef __attribute__((ext_vector_type(4))) float f32x4;

static __device__ __forceinline__ unsigned short f2bf(float x) {
  unsigned int u = __float_as_uint(x);
  return (unsigned short)((u + 0x7FFFu + ((u >> 16) & 1u)) >> 16);  // RNE
}
static __device__ __forceinline__ unsigned int pk2(float a, float b) {
  return (unsigned int)f2bf(a) | ((unsigned int)f2bf(b) << 16);
}

// LDS-only barrier (drains lgkmcnt, NOT vmcnt): global prefetch loads stay in
// flight across it. All cross-wave data flows through LDS.
static __device__ __forceinline__ void barrier_lds() {
  __builtin_amdgcn_sched_barrier(0);
  asm volatile("s_waitcnt lgkmcnt(0)" ::: "memory");
  __builtin_amdgcn_s_barrier();
  __builtin_amdgcn_sched_barrier(0);
}

// k-slot permutation pi: slot m=8g+u holds l = 4g+u (u<4) or 16+4g+(u-4)
// (u>=4) within each 32-l pair; makes the mtile MFMA output order directly
// usable as an A-fragment (M never touches LDS). X^T and (dec*B)^T staged
// with the SAME permutation (MFMA invariant to consistent k-permute).
static __device__ __forceinline__ int invperm(int l) {
  const int jp = l >> 5, v = l & 31;
  return jp * 32 + (v < 16 ? (((v >> 2) << 3) | (v & 3))
                           : ((((v - 16) >> 2) << 3) | 4 | ((v - 16) & 3)));
}

// One block per (b,h), 8 waves, 32 sequential chunks, ONE barrier per chunk.
// ST is now WAVE-LOCAL: every wave redundantly computes S for its own two Y
// p-blocks (fp32 masters stm[2][4] in VGPRs); the Y B-operand fragment is
// built in-register by a 16-lane-group transpose (2 pk2 + 4 shfl). No sSTf/
// sSTb, no cross-wave ST dependency: the barrier only rotates staging bufs.
__global__ __launch_bounds__(512) void ssd_fused(
    const float* __restrict__ Xg, const float* __restrict__ Ag,
    const float* __restrict__ Bg, const float* __restrict__ Cg,
    float* __restrict__ Yg) {
  const int h = blockIdx.x & (NH - 1);
  const int b = blockIdx.x >> 4;
  const int t = threadIdx.x;
  const int w = t >> 6;
  const int lane = t & 63;
  const int g = lane >> 4;
  const int cc = lane & 15;

  __shared__ __align__(16) unsigned short sXt[2][PD][64];       // X^T permuted
  __shared__ __align__(16) unsigned short sB[2][LB][ND + 8];
  __shared__ __align__(16) unsigned short sC[2][LB][ND + 8];    // C' = e_l*C
  __shared__ __align__(16) unsigned short sBdT[2][ND][LB + 8];  // (dec*B)^T perm
  __shared__ float sER[NC][LB];   // exp(+acs)
  __shared__ float sRR[NC][LB];   // exp(-acs)
  __shared__ float sEtot[NC];

  // ---- prologue: decay tables for ALL chunks ----
  {
    float av[4];
#pragma unroll
    for (int k = 0; k < 4; ++k)
      av[k] = Ag[((size_t)(b * SEQL + (w + 8 * k) * LB + lane)) * NH + h];
#pragma unroll
    for (int k = 0; k < 4; ++k) {
      const int c = w + 8 * k;
      float v = av[k];
#pragma unroll
      for (int d = 1; d < 64; d <<= 1) {
        float o = __shfl_up(v, d, 64);
        if (lane >= d) v += o;
      }
      const float e = expf(v);
      sER[c][lane] = e;
      sRR[c][lane] = expf(-v);
      if (lane == 63) sEtot[c] = e;
    }
  }
  __syncthreads();  // tables visible BEFORE STAGE(0,0) reads them (race fix)

  // thread maps
  const int xl0 = (t >> 4) * 2, xp0 = (t & 15) * 4;  // X: 2 l x 4 p
  const int bl = t >> 3, bn0 = (t & 7) * 2;          // B/C: 1 row x 2 n
  const int mX = invperm(xl0);
  const int mB = invperm(bl);
  float4 px0, px1;
  float2 pb2, pc2;

#define PREF(ci) do { \
    const size_t s0_ = (size_t)(b * SEQL + (ci) * LB); \
    px0 = *(const float4*)&Xg[(s0_ + xl0) * NHP + h * PD + xp0]; \
    px1 = *(const float4*)&Xg[(s0_ + xl0 + 1) * NHP + h * PD + xp0]; \
    pb2 = *(const float2*)&Bg[(s0_ + bl) * NHN + h * ND + bn0]; \
    pc2 = *(const float2*)&Cg[(s0_ + bl) * NHN + h * ND + bn0]; \
  } while (0)

#define STAGE(bufi, ci) do { \
    _Pragma("unroll") \
    for (int j_ = 0; j_ < 4; ++j_) { \
      const int p_ = xp0 + j_; \
      const int mm_ = ((((mX >> 3) ^ (p_ & 7)) << 3) | (mX & 7)); \
      *(unsigned int*)&sXt[bufi][p_][mm_] = pk2((&px0.x)[j_], (&px1.x)[j_]); \
    } \
    { const float el_ = sER[ci][bl]; \
      const float dl_ = sEtot[ci] * sRR[ci][bl]; \
      *(unsigned int*)&sB[bufi][bl][bn0] = pk2(pb2.x, pb2.y); \
      *(unsigned int*)&sC[bufi][bl][bn0] = pk2(el_ * pc2.x, el_ * pc2.y); \
      sBdT[bufi][bn0][mB] = f2bf(dl_ * pb2.x); \
      sBdT[bufi][bn0 + 1][mB] = f2bf(dl_ * pb2.y); } \
  } while (0)

  const bf16x8 zf8 = {0, 0, 0, 0, 0, 0, 0, 0};
  auto xfrag = [&](int buf, int p_, int kb) -> bf16x8 {
    return *(const bf16x8*)&sXt[buf][p_][(kb ^ (p_ & 7)) << 3];
  };

  PREF(0);
  STAGE(0, 0);
  PREF(1);
  barrier_lds();  // stage(0) visible

  const int lb = w >> 1;            // l-block owned by this wave's pair
  const int pb0 = (w & 1) * 2;      // first of two Y p-blocks
  const int l = lb * 16 + cc;

  // wave-local ST masters: stm[pbi][r] = ST[n = 4g+r][p = (pb0+pbi)*16+cc]
  float stm[2][4];
#pragma unroll
  for (int i = 0; i < 2; ++i)
#pragma unroll
    for (int r = 0; r < 4; ++r) stm[i][r] = 0.f;

  for (int c = 0; c < NC; ++c) {
    const int db = c & 1, nb = db ^ 1;

    // ---- build Y's ST B-operand frags from stm (in-register transpose) ----
    // lane (g,cc) holds S[4g..4g+3][cc]; target: lane (g,cc) holds
    // ST[p][n = g*8 .. g*8+7] (g<2).  g=0: own(n0-3) + lane+16(n4-7);
    // g=1: lane+16 (g=2: n8-11) + lane+32 (g=3: n12-15).
    bf16x8 stf[2];
#pragma unroll
    for (int pbi = 0; pbi < 2; ++pbi) {
      const unsigned int w0 = pk2(stm[pbi][0], stm[pbi][1]);
      const unsigned int w1 = pk2(stm[pbi][2], stm[pbi][3]);
      const unsigned int a0 = __shfl(w0, (lane + 16) & 63, 64);
      const unsigned int a1 = __shfl(w1, (lane + 16) & 63, 64);
      const unsigned int b0 = __shfl(w0, (lane + 32) & 63, 64);
      const unsigned int b1 = __shfl(w1, (lane + 32) & 63, 64);
      union { bf16x8 v; unsigned int u[4]; } f;
      if (g == 0) {
        f.u[0] = w0; f.u[1] = w1; f.u[2] = a0; f.u[3] = a1;
      } else if (g == 1) {
        f.u[0] = a0; f.u[1] = a1; f.u[2] = b0; f.u[3] = b1;
      } else {
        f.u[0] = 0u; f.u[1] = 0u; f.u[2] = 0u; f.u[3] = 0u;
      }
      stf[pbi] = f.v;
    }

    // ---- M-frags in registers (redundant within wave pair) ----
    bf16x8 cf = zf8;
    if (g < 2) cf = *(const bf16x8*)&sC[db][l][g * 8];
    auto mtile = [&](int sb, bool mask) -> uint2 {
      bf16x8 bfr = zf8;
      if (g < 2) bfr = *(const bf16x8*)&sB[db][sb * 16 + cc][g * 8];
      f32x4 z4 = {0.f, 0.f, 0.f, 0.f};
      f32x4 d = __builtin_amdgcn_mfma_f32_16x16x32_bf16(bfr, cf, z4, 0, 0, 0);
      // lane holds D'[s = sb*16+4g+r][l]
      float m[4];
#pragma unroll
      for (int r = 0; r < 4; ++r) {
        m[r] = d[r] * sRR[c][sb * 16 + 4 * g + r];
        if (mask && (4 * g + r) > cc) m[r] = 0.f;
      }
      return make_uint2(pk2(m[0], m[1]), pk2(m[2], m[3]));
    };
    union { bf16x8 v; unsigned int u[4]; } mf0, mf1;
    mf0.u[0] = mf0.u[1] = mf0.u[2] = mf0.u[3] = 0u;
    mf1.u[0] = mf1.u[1] = mf1.u[2] = mf1.u[3] = 0u;
    if (lb == 0) {
      const uint2 t0 = mtile(0, true);
      mf0.u[0] = t0.x; mf0.u[1] = t0.y;
    } else if (lb == 1) {
      const uint2 t0 = mtile(0, false), t1 = mtile(1, true);
      mf0.u[0] = t0.x; mf0.u[1] = t0.y; mf0.u[2] = t1.x; mf0.u[3] = t1.y;
    } else if (lb == 2) {
      const uint2 t0 = mtile(0, false), t1 = mtile(1, false), t2 = mtile(2, true);
      mf0.u[0] = t0.x; mf0.u[1] = t0.y; mf0.u[2] = t1.x; mf0.u[3] = t1.y;
      mf1.u[0] = t2.x; mf1.u[1] = t2.y;
    } else {
      const uint2 t0 = mtile(0, false), t1 = mtile(1, false);
      const uint2 t2 = mtile(2, false), t3 = mtile(3, true);
      mf0.u[0] = t0.x; mf0.u[1] = t0.y; mf0.u[2] = t1.x; mf0.u[3] = t1.y;
      mf1.u[0] = t2.x; mf1.u[1] = t2.y; mf1.u[2] = t3.x; mf1.u[3] = t3.y;
    }

    // ---- Y tiles: 2 p-blocks per wave ----
#pragma unroll
    for (int pbi = 0; pbi < 2; ++pbi) {
      const int p = (pb0 + pbi) * 16 + cc;
      f32x4 acc = {0.f, 0.f, 0.f, 0.f};
      acc = __builtin_amdgcn_mfma_f32_16x16x32_bf16(cf, stf[pbi], acc, 0, 0, 0);
      acc = __builtin_amdgcn_mfma_f32_16x16x32_bf16(mf0.v, xfrag(db, p, g), acc, 0, 0, 0);
      if (lb >= 2)
        acc = __builtin_amdgcn_mfma_f32_16x16x32_bf16(mf1.v, xfrag(db, p, 4 + g), acc, 0, 0, 0);
      const size_t yb =
          ((size_t)(b * SEQL + c * LB + lb * 16 + 4 * g)) * NHP + h * PD + p;
#pragma unroll
      for (int r = 0; r < 4; ++r) Yg[yb + (size_t)r * NHP] = acc[r];
    }

    // ---- S update, wave-local, both own p-blocks ----
    {
      bf16x8 ad0 = *(const bf16x8*)&sBdT[db][cc][g * 8];
      bf16x8 ad1 = *(const bf16x8*)&sBdT[db][cc][32 + g * 8];
      const float etot = sEtot[c];
#pragma unroll
      for (int pbi = 0; pbi < 2; ++pbi) {
        const int p = (pb0 + pbi) * 16 + cc;
        f32x4 s4 = {0.f, 0.f, 0.f, 0.f};
        s4 = __builtin_amdgcn_mfma_f32_16x16x32_bf16(ad0, xfrag(db, p, g), s4, 0, 0, 0);
        s4 = __builtin_amdgcn_mfma_f32_16x16x32_bf16(ad1, xfrag(db, p, 4 + g), s4, 0, 0, 0);
#pragma unroll
        for (int r = 0; r < 4; ++r) stm[pbi][r] = stm[pbi][r] * etot + s4[r];
      }
    }

    // ---- stage chunk c+1 into buf nb (overlaps compute above) ----
    if (c + 1 < NC) {
      STAGE(nb, c + 1);
      if (c + 2 < NC) PREF(c + 2);
    }
    barrier_lds();  // end of window: staged data visible
  }
#undef PREF
#undef STAGE
}

extern "C" void kernel_launch(void* const* d_in, const int* in_sizes, int n_in,
                              void* d_out, int out_size, void* d_ws, size_t ws_size,
                              hipStream_t stream) {
  (void)in_sizes; (void)n_in; (void)out_size; (void)d_ws; (void)ws_size;
  const float* X = (const float*)d_in[0];
  const float* A = (const float*)d_in[1];
  const float* B = (const float*)d_in[2];
  const float* C = (const float*)d_in[3];
  float* Y = (float*)d_out;
  ssd_fused<<<BS * NH, 512, 0, stream>>>(X, A, B, C, Y);
}